// Round 12
// baseline (155.284 us; speedup 1.0000x reference)
//
#include <hip/hip_runtime.h>
#include <math.h>

#define NAGENT 4096
#define TOPK 32
#define FAGB 16   // agents per block in fused kernel (4 rounds x 4 waves)
#define CANDCAP 2048

// ---------------------------------------------------------------------------
// Kernel 1: exact top-32 nearest neighbors.
// R12: fully parallel cutoff (wave shfl_up scan + cross-wave fixup) replaces
// the t==0 serial walks (~44 dependent LDS reads -> ~6). Keys/superset/rank
// unchanged -> selection bit-identical to R9/R11 (PASSED).
// ---------------------------------------------------------------------------
__global__ __launch_bounds__(256) void topk_kernel(
    const float* __restrict__ states, int* __restrict__ idx_out)
{
    const int i = blockIdx.x;
    const int t = threadIdx.x;
    const int lane = t & 63;
    __shared__ unsigned int hist[1024];
    __shared__ unsigned int wsum[4];
    __shared__ unsigned long long cand[CANDCAP];
    __shared__ int ccount;
    __shared__ unsigned int cutB;

    #pragma unroll
    for (int u = 0; u < 4; ++u) hist[t + u * 256] = 0u;
    if (t == 0) ccount = 0;

    const float4 si = ((const float4*)states)[i];
    __syncthreads();

    unsigned int mybits[16];
    #pragma unroll
    for (int u = 0; u < 16; ++u) {
        int j = t + u * 256;
        float4 sj = ((const float4*)states)[j];
        float dx = __fsub_rn(si.x, sj.x);
        float dy = __fsub_rn(si.y, sj.y);
        float s  = __fadd_rn(__fadd_rn(__fmul_rn(dx, dx), __fmul_rn(dy, dy)), 1e-4f);
        float dv = sqrtf(s);
        mybits[u] = __float_as_uint(dv);
        unsigned int bin = (unsigned int)(dv * 256.0f);
        if (bin > 1023u) bin = 1023u;
        atomicAdd(&hist[bin], 1u);
    }
    __syncthreads();

    // thread t owns bins [4t, 4t+4); parallel exclusive prefix over groups
    unsigned int h0 = hist[t * 4 + 0], h1 = hist[t * 4 + 1];
    unsigned int h2 = hist[t * 4 + 2], h3 = hist[t * 4 + 3];
    unsigned int v = h0 + h1 + h2 + h3;
    unsigned int inc = v;
    #pragma unroll
    for (int off = 1; off < 64; off <<= 1) {
        unsigned int u = __shfl_up(inc, off, 64);
        if (lane >= off) inc += u;
    }
    if (lane == 63) wsum[t >> 6] = inc;
    __syncthreads();
    unsigned int woff = 0;
    for (int w = 0; w < (t >> 6); ++w) woff += wsum[w];
    unsigned int incl = inc + woff;
    unsigned int exc  = incl - v;
    if (exc < TOPK && incl >= TOPK) {     // exactly one thread
        unsigned int cum = exc;
        unsigned int hh[4] = {h0, h1, h2, h3};
        int b = t * 4 + 3;
        #pragma unroll
        for (int q = 0; q < 4; ++q) {
            cum += hh[q];
            if (cum >= TOPK) { b = t * 4 + q; break; }
        }
        cutB = (unsigned int)b;
    }
    __syncthreads();

    const unsigned int B = cutB;
    #pragma unroll
    for (int u = 0; u < 16; ++u) {
        float dv = __uint_as_float(mybits[u]);
        unsigned int bin = (unsigned int)(dv * 256.0f);
        if (bin > 1023u) bin = 1023u;
        if (bin <= B) {
            int pos = atomicAdd(&ccount, 1);
            if (pos < CANDCAP)
                cand[pos] = ((unsigned long long)mybits[u] << 32)
                          | (unsigned int)(t + u * 256);
        }
    }
    __syncthreads();

    const int C = (ccount < CANDCAP) ? ccount : CANDCAP;
    for (int q = t; q < C; q += 256) {
        unsigned long long key = cand[q];
        int rank = 0;
        for (int r = 0; r < C; ++r) rank += (cand[r] < key) ? 1 : 0;
        if (rank < TOPK) idx_out[i * TOPK + rank] = (int)(key & 0xffffffffu);
    }
}

// ---------------------------------------------------------------------------
// Kernel 2 (fused): conv stack + argmax + dense MLP -> out. 16 agents/block
// (4 rounds x 4 wave-private agents): staging amortized 2x vs R11.
// b2 read direct from global (saves LDS; 8 scalar L1 reads/lane/agent).
// LDS ~80.6 KB -> 2 blocks/CU. FMA chain orders identical to R8/R9/R11.
// ---------------------------------------------------------------------------
__global__ __launch_bounds__(256) void fused_kernel(
    const float* __restrict__ states, const float* __restrict__ goals,
    const float* __restrict__ W1,  const float* __restrict__ b1,
    const float* __restrict__ W2,  const float* __restrict__ b2,
    const float* __restrict__ Wd1, const float* __restrict__ bd1,
    const float* __restrict__ Wd2, const float* __restrict__ bd2,
    const float* __restrict__ Wd3, const float* __restrict__ bd3,
    const float* __restrict__ Wd4, const float* __restrict__ bd4,
    const int* __restrict__ idx_in, float* __restrict__ out)
{
    const int t = threadIdx.x;
    const int a = t >> 6;               // wave id
    const int l = t & 63;
    const int base = blockIdx.x * FAGB;

    __shared__ __attribute__((aligned(16))) float w2a[64 * 68];    // 17 KB
    __shared__ __attribute__((aligned(16))) float w2b[64 * 68];    // 17 KB
    __shared__ __attribute__((aligned(16))) float w1s[320];
    __shared__ __attribute__((aligned(16))) float b1s[64];
    __shared__ __attribute__((aligned(16))) float flat[4][160];
    __shared__ __attribute__((aligned(16))) float maskv[4][32];
    __shared__ __attribute__((aligned(16))) float featb[FAGB][132]; // 8.4 KB
    __shared__ __attribute__((aligned(16))) float h1[4][2048];      // 32 KB
    // dense-phase z-buffers carved from h1 (dead after the rounds):
    float* z1s = &h1[0][0];            // 16*64  = 1024 floats
    float* z2s = z1s + 1024;           // 16*128 = 2048 floats
    float* z3s = z2s + 2048;           // 16*64  = 1024 floats
    float* kvs = z3s + 1024;           // 16*4   = 64 floats

    // ---- stage W2 split + small weights
    #pragma unroll
    for (int u = 0; u < 32; ++u) {
        int e = t + u * 256;
        int o = e >> 6, c = e & 63;
        float v = W2[e];
        int dst = c * 68 + ((o >> 3) << 2) + (o & 3);
        if (o & 4) w2b[dst] = v; else w2a[dst] = v;
    }
    for (int e = t; e < 320; e += 256) w1s[e] = W1[e];
    if (t < 64) b1s[t] = b1[t];
    __syncthreads();   // staging visible; below is wave-private until pre-dense

    #pragma unroll
    for (int round = 0; round < 4; ++round) {
        const int g = round * 4 + a;       // local agent index
        const int i = base + g;            // global agent

        if (l < 32) {
            int j = idx_in[i * TOPK + l];
            float4 sj  = ((const float4*)states)[j];
            float4 siv = ((const float4*)states)[i];
            float d0 = siv.x - sj.x;
            float d1 = siv.y - sj.y;
            float d2 = siv.z - sj.z;
            float d3 = siv.w - sj.w;
            flat[a][l * 5 + 0] = d0;
            flat[a][l * 5 + 1] = d1;
            flat[a][l * 5 + 2] = d2;
            flat[a][l * 5 + 3] = d3;
            flat[a][l * 5 + 4] = (j == i) ? 1.0f : 0.0f;
            float dist = sqrtf(__fadd_rn(__fmul_rn(d0, d0), __fmul_rn(d1, d1)));
            maskv[a][l] = (dist < 1.0f) ? 1.0f : 0.0f;
        } else if (l < 36) {
            int f = l - 32;
            float4 siv = ((const float4*)states)[i];
            float2 gi  = ((const float2*)goals)[i];
            float v = (f == 0) ? (siv.x - gi.x)
                    : (f == 1) ? (siv.y - gi.y)
                    : (f == 2) ? siv.z : siv.w;
            featb[g][128 + f] = v;
        }

        // ---- h1 (wave-private)
        #pragma unroll
        for (int u = 0; u < 32; ++u) {
            int e = u * 64 + l;
            int p = e & 31, o1 = e >> 5;
            float acc = b1s[o1];
            #pragma unroll
            for (int f = 0; f < 5; ++f)
                acc += w1s[o1 * 5 + f] * flat[a][f * 32 + p];
            h1[a][o1 * 32 + p] = fmaxf(acc, 0.0f);
        }

        // ---- h2: lane owns o in [ow*8,+8), p in [pt*8,+8)
        const int ow = l & 15;
        const int pt = l >> 4;
        float acc[8][8];
        #pragma unroll
        for (int k = 0; k < 8; ++k)
            #pragma unroll
            for (int q = 0; q < 8; ++q) acc[k][q] = 0.0f;

        for (int c = 0; c < 64; ++c) {
            float4 wA = *(const float4*)&w2a[c * 68 + ow * 4];
            float4 wB = *(const float4*)&w2b[c * 68 + ow * 4];
            float4 hA = *(const float4*)&h1[a][c * 32 + pt * 8];
            float4 hB = *(const float4*)&h1[a][c * 32 + pt * 8 + 4];
            float wv[8] = {wA.x, wA.y, wA.z, wA.w, wB.x, wB.y, wB.z, wB.w};
            float hv[8] = {hA.x, hA.y, hA.z, hA.w, hB.x, hB.y, hB.z, hB.w};
            #pragma unroll
            for (int k = 0; k < 8; ++k)
                #pragma unroll
                for (int q = 0; q < 8; ++q)
                    acc[k][q] += wv[k] * hv[q];
        }

        // ---- bias + relu + mask + argmax; b2 direct from global (L1)
        float4 mA = *(const float4*)&maskv[a][pt * 8];
        float4 mB = *(const float4*)&maskv[a][pt * 8 + 4];
        float mv[8] = {mA.x, mA.y, mA.z, mA.w, mB.x, mB.y, mB.z, mB.w};
        #pragma unroll
        for (int k = 0; k < 8; ++k) {
            float bb = b2[ow * 8 + k];
            unsigned long long best = 0ull;
            #pragma unroll
            for (int q = 0; q < 8; ++q) {
                float val = fmaxf(acc[k][q] + bb, 0.0f) * mv[q];
                unsigned long long key =
                    ((unsigned long long)__float_as_uint(val) << 32)
                    | (unsigned int)(31 - (pt * 8 + q));
                if (key > best) best = key;
            }
            unsigned long long o1 = __shfl_xor(best, 16, 64); if (o1 > best) best = o1;
            unsigned long long o2 = __shfl_xor(best, 32, 64); if (o2 > best) best = o2;
            if (pt == 0) {
                int pbest = 31 - (int)(best & 63ull);
                featb[g][ow * 8 + k] = (float)pbest;
            }
        }
    }
    __syncthreads();   // featb (all 16 agents) visible to all waves

    // ---- dense phase: wave a handles local agents gbase..gbase+3 (R9 order)
    const int gbase = a * 4;

    // L1
    {
        float bb = bd1[l];
        float a0 = bb, a1 = bb, a2 = bb, a3 = bb;
        for (int k = 0; k < 33; ++k) {
            float4 wv = *(const float4*)&Wd1[l * 132 + 4 * k];
            float4 f0 = *(const float4*)&featb[gbase + 0][4 * k];
            float4 f1 = *(const float4*)&featb[gbase + 1][4 * k];
            float4 f2 = *(const float4*)&featb[gbase + 2][4 * k];
            float4 f3 = *(const float4*)&featb[gbase + 3][4 * k];
            a0 += wv.x * f0.x; a0 += wv.y * f0.y; a0 += wv.z * f0.z; a0 += wv.w * f0.w;
            a1 += wv.x * f1.x; a1 += wv.y * f1.y; a1 += wv.z * f1.z; a1 += wv.w * f1.w;
            a2 += wv.x * f2.x; a2 += wv.y * f2.y; a2 += wv.z * f2.z; a2 += wv.w * f2.w;
            a3 += wv.x * f3.x; a3 += wv.y * f3.y; a3 += wv.z * f3.z; a3 += wv.w * f3.w;
        }
        z1s[(gbase + 0) * 64 + l] = fmaxf(a0, 0.0f);
        z1s[(gbase + 1) * 64 + l] = fmaxf(a1, 0.0f);
        z1s[(gbase + 2) * 64 + l] = fmaxf(a2, 0.0f);
        z1s[(gbase + 3) * 64 + l] = fmaxf(a3, 0.0f);
    }

    // L2
    {
        float accA[4], accB[4];
        float bA = bd2[l], bB = bd2[l + 64];
        #pragma unroll
        for (int g = 0; g < 4; ++g) { accA[g] = bA; accB[g] = bB; }
        for (int k = 0; k < 16; ++k) {
            float4 wa = *(const float4*)&Wd2[l * 64 + 4 * k];
            float4 wb = *(const float4*)&Wd2[(l + 64) * 64 + 4 * k];
            #pragma unroll
            for (int g = 0; g < 4; ++g) {
                float4 f = *(const float4*)&z1s[(gbase + g) * 64 + 4 * k];
                accA[g] += wa.x * f.x; accA[g] += wa.y * f.y;
                accA[g] += wa.z * f.z; accA[g] += wa.w * f.w;
                accB[g] += wb.x * f.x; accB[g] += wb.y * f.y;
                accB[g] += wb.z * f.z; accB[g] += wb.w * f.w;
            }
        }
        #pragma unroll
        for (int g = 0; g < 4; ++g) {
            z2s[(gbase + g) * 128 + l]      = fmaxf(accA[g], 0.0f);
            z2s[(gbase + g) * 128 + l + 64] = fmaxf(accB[g], 0.0f);
        }
    }

    // L3
    {
        float acc[4];
        float bb = bd3[l];
        #pragma unroll
        for (int g = 0; g < 4; ++g) acc[g] = bb;
        for (int k = 0; k < 32; ++k) {
            float4 wv = *(const float4*)&Wd3[l * 128 + 4 * k];
            #pragma unroll
            for (int g = 0; g < 4; ++g) {
                float4 f = *(const float4*)&z2s[(gbase + g) * 128 + 4 * k];
                acc[g] += wv.x * f.x; acc[g] += wv.y * f.y;
                acc[g] += wv.z * f.z; acc[g] += wv.w * f.w;
            }
        }
        #pragma unroll
        for (int g = 0; g < 4; ++g)
            z3s[(gbase + g) * 64 + l] = fmaxf(acc[g], 0.0f);
    }

    // L4 + sigmoid -> kvs (lanes 0..15: agent g=l>>2, gain o=l&3)
    if (l < 16) {
        int g = gbase + (l >> 2), o = l & 3;
        float acc = bd4[o];
        for (int c = 0; c < 64; ++c) acc += Wd4[o * 64 + c] * z3s[g * 64 + c];
        kvs[g * 4 + o] = 2.0f / (1.0f + expf(-acc)) + 0.2f;
    }
    // same-wave LDS RAW (R11-proven: compiler inserts lgkmcnt waits)
    if (l < 8) {
        int g = gbase + (l >> 1), axis = l & 1;
        float ka = kvs[g * 4 + 2 * axis + 0];
        float kb = kvs[g * 4 + 2 * axis + 1];
        float rel = featb[g][128 + axis];
        float vel = featb[g][130 + axis];
        out[(base + g) * 2 + axis] = -(ka * rel + kb * vel);
    }
}

extern "C" void kernel_launch(void* const* d_in, const int* in_sizes, int n_in,
                              void* d_out, int out_size, void* d_ws, size_t ws_size,
                              hipStream_t stream)
{
    const float* states = (const float*)d_in[0];
    const float* goals  = (const float*)d_in[1];
    const float* W1  = (const float*)d_in[2];
    const float* b1  = (const float*)d_in[3];
    const float* W2  = (const float*)d_in[4];
    const float* b2  = (const float*)d_in[5];
    const float* Wd1 = (const float*)d_in[6];
    const float* bd1 = (const float*)d_in[7];
    const float* Wd2 = (const float*)d_in[8];
    const float* bd2 = (const float*)d_in[9];
    const float* Wd3 = (const float*)d_in[10];
    const float* bd3 = (const float*)d_in[11];
    const float* Wd4 = (const float*)d_in[12];
    const float* bd4 = (const float*)d_in[13];

    int*   idx = (int*)d_ws;   // 512 KB
    float* out = (float*)d_out;

    topk_kernel<<<NAGENT, 256, 0, stream>>>(states, idx);
    fused_kernel<<<NAGENT / FAGB, 256, 0, stream>>>(states, goals, W1, b1, W2, b2,
                                                    Wd1, bd1, Wd2, bd2, Wd3, bd3,
                                                    Wd4, bd4, idx, out);
}

// Round 13
// 140.263 us; speedup vs baseline: 1.1071x; 1.1071x over previous
//
#include <hip/hip_runtime.h>
#include <math.h>

#define NAGENT 4096
#define TOPK 32
#define FAGB 8    // agents per block in fused kernel (2 rounds x 4 waves)
#define CANDCAP 2048

// ---------------------------------------------------------------------------
// Kernel 1: exact top-32 nearest neighbors. VERBATIM from R12 (PASSED).
// ---------------------------------------------------------------------------
__global__ __launch_bounds__(256) void topk_kernel(
    const float* __restrict__ states, int* __restrict__ idx_out)
{
    const int i = blockIdx.x;
    const int t = threadIdx.x;
    const int lane = t & 63;
    __shared__ unsigned int hist[1024];
    __shared__ unsigned int wsum[4];
    __shared__ unsigned long long cand[CANDCAP];
    __shared__ int ccount;
    __shared__ unsigned int cutB;

    #pragma unroll
    for (int u = 0; u < 4; ++u) hist[t + u * 256] = 0u;
    if (t == 0) ccount = 0;

    const float4 si = ((const float4*)states)[i];
    __syncthreads();

    unsigned int mybits[16];
    #pragma unroll
    for (int u = 0; u < 16; ++u) {
        int j = t + u * 256;
        float4 sj = ((const float4*)states)[j];
        float dx = __fsub_rn(si.x, sj.x);
        float dy = __fsub_rn(si.y, sj.y);
        float s  = __fadd_rn(__fadd_rn(__fmul_rn(dx, dx), __fmul_rn(dy, dy)), 1e-4f);
        float dv = sqrtf(s);
        mybits[u] = __float_as_uint(dv);
        unsigned int bin = (unsigned int)(dv * 256.0f);
        if (bin > 1023u) bin = 1023u;
        atomicAdd(&hist[bin], 1u);
    }
    __syncthreads();

    unsigned int h0 = hist[t * 4 + 0], h1 = hist[t * 4 + 1];
    unsigned int h2 = hist[t * 4 + 2], h3 = hist[t * 4 + 3];
    unsigned int v = h0 + h1 + h2 + h3;
    unsigned int inc = v;
    #pragma unroll
    for (int off = 1; off < 64; off <<= 1) {
        unsigned int u = __shfl_up(inc, off, 64);
        if (lane >= off) inc += u;
    }
    if (lane == 63) wsum[t >> 6] = inc;
    __syncthreads();
    unsigned int woff = 0;
    for (int w = 0; w < (t >> 6); ++w) woff += wsum[w];
    unsigned int incl = inc + woff;
    unsigned int exc  = incl - v;
    if (exc < TOPK && incl >= TOPK) {
        unsigned int cum = exc;
        unsigned int hh[4] = {h0, h1, h2, h3};
        int b = t * 4 + 3;
        #pragma unroll
        for (int q = 0; q < 4; ++q) {
            cum += hh[q];
            if (cum >= TOPK) { b = t * 4 + q; break; }
        }
        cutB = (unsigned int)b;
    }
    __syncthreads();

    const unsigned int B = cutB;
    #pragma unroll
    for (int u = 0; u < 16; ++u) {
        float dv = __uint_as_float(mybits[u]);
        unsigned int bin = (unsigned int)(dv * 256.0f);
        if (bin > 1023u) bin = 1023u;
        if (bin <= B) {
            int pos = atomicAdd(&ccount, 1);
            if (pos < CANDCAP)
                cand[pos] = ((unsigned long long)mybits[u] << 32)
                          | (unsigned int)(t + u * 256);
        }
    }
    __syncthreads();

    const int C = (ccount < CANDCAP) ? ccount : CANDCAP;
    for (int q = t; q < C; q += 256) {
        unsigned long long key = cand[q];
        int rank = 0;
        for (int r = 0; r < C; ++r) rank += (cand[r] < key) ? 1 : 0;
        if (rank < TOPK) idx_out[i * TOPK + rank] = (int)(key & 0xffffffffu);
    }
}

// ---------------------------------------------------------------------------
// Kernel 2 (fused): R11 structure exactly (FAGB=8, 77.3 KB -> 2 blocks/CU;
// R12's 80.9 KB tipped the LDS cliff to 1 block/CU, -25%). One change vs R11:
// h2 c-loop unrolled x4 -- 16 ds_read_b128 in flight per 256 FMAs (was 4/64)
// for in-wave latency hiding. Per-accumulator c order unchanged -> bitwise
// identical output.
// ---------------------------------------------------------------------------
__global__ __launch_bounds__(256) void fused_kernel(
    const float* __restrict__ states, const float* __restrict__ goals,
    const float* __restrict__ W1,  const float* __restrict__ b1,
    const float* __restrict__ W2,  const float* __restrict__ b2,
    const float* __restrict__ Wd1, const float* __restrict__ bd1,
    const float* __restrict__ Wd2, const float* __restrict__ bd2,
    const float* __restrict__ Wd3, const float* __restrict__ bd3,
    const float* __restrict__ Wd4, const float* __restrict__ bd4,
    const int* __restrict__ idx_in, float* __restrict__ out)
{
    const int t = threadIdx.x;
    const int a = t >> 6;               // wave id
    const int l = t & 63;
    const int base = blockIdx.x * FAGB;

    __shared__ __attribute__((aligned(16))) float w2a[64 * 68];    // 17 KB
    __shared__ __attribute__((aligned(16))) float w2b[64 * 68];    // 17 KB
    __shared__ __attribute__((aligned(16))) float w1s[320];
    __shared__ __attribute__((aligned(16))) float b1s[64];
    __shared__ __attribute__((aligned(16))) float b2s[128];
    __shared__ __attribute__((aligned(16))) float flat[4][160];
    __shared__ __attribute__((aligned(16))) float maskv[4][32];
    __shared__ __attribute__((aligned(16))) float featb[FAGB][132]; // 4.2 KB
    __shared__ __attribute__((aligned(16))) float h1[4][2048];      // 32 KB
    float* z1s = &h1[0][0];            // 8*64  = 512 floats (dead h1 space)
    float* z2s = z1s + 512;            // 8*128 = 1024
    float* z3s = z2s + 1024;           // 8*64  = 512
    float* kvs = z3s + 512;            // 8*4   = 32

    // ---- stage W2 split + small weights
    #pragma unroll
    for (int u = 0; u < 32; ++u) {
        int e = t + u * 256;
        int o = e >> 6, c = e & 63;
        float v = W2[e];
        int dst = c * 68 + ((o >> 3) << 2) + (o & 3);
        if (o & 4) w2b[dst] = v; else w2a[dst] = v;
    }
    for (int e = t; e < 320; e += 256) w1s[e] = W1[e];
    if (t < 64)  b1s[t] = b1[t];
    if (t < 128) b2s[t] = b2[t];
    __syncthreads();

    #pragma unroll
    for (int round = 0; round < 2; ++round) {
        const int g = round * 4 + a;
        const int i = base + g;

        if (l < 32) {
            int j = idx_in[i * TOPK + l];
            float4 sj  = ((const float4*)states)[j];
            float4 siv = ((const float4*)states)[i];
            float d0 = siv.x - sj.x;
            float d1 = siv.y - sj.y;
            float d2 = siv.z - sj.z;
            float d3 = siv.w - sj.w;
            flat[a][l * 5 + 0] = d0;
            flat[a][l * 5 + 1] = d1;
            flat[a][l * 5 + 2] = d2;
            flat[a][l * 5 + 3] = d3;
            flat[a][l * 5 + 4] = (j == i) ? 1.0f : 0.0f;
            float dist = sqrtf(__fadd_rn(__fmul_rn(d0, d0), __fmul_rn(d1, d1)));
            maskv[a][l] = (dist < 1.0f) ? 1.0f : 0.0f;
        } else if (l < 36) {
            int f = l - 32;
            float4 siv = ((const float4*)states)[i];
            float2 gi  = ((const float2*)goals)[i];
            float v = (f == 0) ? (siv.x - gi.x)
                    : (f == 1) ? (siv.y - gi.y)
                    : (f == 2) ? siv.z : siv.w;
            featb[g][128 + f] = v;
        }

        // ---- h1 (wave-private)
        #pragma unroll
        for (int u = 0; u < 32; ++u) {
            int e = u * 64 + l;
            int p = e & 31, o1 = e >> 5;
            float acc = b1s[o1];
            #pragma unroll
            for (int f = 0; f < 5; ++f)
                acc += w1s[o1 * 5 + f] * flat[a][f * 32 + p];
            h1[a][o1 * 32 + p] = fmaxf(acc, 0.0f);
        }

        // ---- h2: lane owns o in [ow*8,+8), p in [pt*8,+8); c-loop unroll x4
        const int ow = l & 15;
        const int pt = l >> 4;
        float acc[8][8];
        #pragma unroll
        for (int k = 0; k < 8; ++k)
            #pragma unroll
            for (int q = 0; q < 8; ++q) acc[k][q] = 0.0f;

        for (int c4 = 0; c4 < 16; ++c4) {
            float4 wAv[4], wBv[4], hAv[4], hBv[4];
            #pragma unroll
            for (int cc = 0; cc < 4; ++cc) {
                int c = c4 * 4 + cc;
                wAv[cc] = *(const float4*)&w2a[c * 68 + ow * 4];
                wBv[cc] = *(const float4*)&w2b[c * 68 + ow * 4];
                hAv[cc] = *(const float4*)&h1[a][c * 32 + pt * 8];
                hBv[cc] = *(const float4*)&h1[a][c * 32 + pt * 8 + 4];
            }
            #pragma unroll
            for (int cc = 0; cc < 4; ++cc) {
                float wv[8] = {wAv[cc].x, wAv[cc].y, wAv[cc].z, wAv[cc].w,
                               wBv[cc].x, wBv[cc].y, wBv[cc].z, wBv[cc].w};
                float hv[8] = {hAv[cc].x, hAv[cc].y, hAv[cc].z, hAv[cc].w,
                               hBv[cc].x, hBv[cc].y, hBv[cc].z, hBv[cc].w};
                #pragma unroll
                for (int k = 0; k < 8; ++k)
                    #pragma unroll
                    for (int q = 0; q < 8; ++q)
                        acc[k][q] += wv[k] * hv[q];
            }
        }

        // ---- bias + relu + mask + argmax (first-max via key)
        float4 mA = *(const float4*)&maskv[a][pt * 8];
        float4 mB = *(const float4*)&maskv[a][pt * 8 + 4];
        float mv[8] = {mA.x, mA.y, mA.z, mA.w, mB.x, mB.y, mB.z, mB.w};
        #pragma unroll
        for (int k = 0; k < 8; ++k) {
            float bb = b2s[ow * 8 + k];
            unsigned long long best = 0ull;
            #pragma unroll
            for (int q = 0; q < 8; ++q) {
                float val = fmaxf(acc[k][q] + bb, 0.0f) * mv[q];
                unsigned long long key =
                    ((unsigned long long)__float_as_uint(val) << 32)
                    | (unsigned int)(31 - (pt * 8 + q));
                if (key > best) best = key;
            }
            unsigned long long o1 = __shfl_xor(best, 16, 64); if (o1 > best) best = o1;
            unsigned long long o2 = __shfl_xor(best, 32, 64); if (o2 > best) best = o2;
            if (pt == 0) {
                int pbest = 31 - (int)(best & 63ull);
                featb[g][ow * 8 + k] = (float)pbest;
            }
        }
    }
    __syncthreads();   // featb (all 8 agents) visible to all waves

    // ---- dense phase: wave a handles local agents g0=2a, g1=2a+1 (R11 exact)
    const int g0 = 2 * a, g1 = 2 * a + 1;

    {
        float bb = bd1[l];
        float a0 = bb, a1 = bb;
        for (int k = 0; k < 33; ++k) {
            float4 wv = *(const float4*)&Wd1[l * 132 + 4 * k];
            float4 f0 = *(const float4*)&featb[g0][4 * k];
            float4 f1 = *(const float4*)&featb[g1][4 * k];
            a0 += wv.x * f0.x; a0 += wv.y * f0.y; a0 += wv.z * f0.z; a0 += wv.w * f0.w;
            a1 += wv.x * f1.x; a1 += wv.y * f1.y; a1 += wv.z * f1.z; a1 += wv.w * f1.w;
        }
        z1s[g0 * 64 + l] = fmaxf(a0, 0.0f);
        z1s[g1 * 64 + l] = fmaxf(a1, 0.0f);
    }

    {
        float accA0 = bd2[l], accA1 = bd2[l];
        float accB0 = bd2[l + 64], accB1 = bd2[l + 64];
        for (int k = 0; k < 16; ++k) {
            float4 wa = *(const float4*)&Wd2[l * 64 + 4 * k];
            float4 wb = *(const float4*)&Wd2[(l + 64) * 64 + 4 * k];
            float4 f0 = *(const float4*)&z1s[g0 * 64 + 4 * k];
            float4 f1 = *(const float4*)&z1s[g1 * 64 + 4 * k];
            accA0 += wa.x * f0.x; accA0 += wa.y * f0.y;
            accA0 += wa.z * f0.z; accA0 += wa.w * f0.w;
            accB0 += wb.x * f0.x; accB0 += wb.y * f0.y;
            accB0 += wb.z * f0.z; accB0 += wb.w * f0.w;
            accA1 += wa.x * f1.x; accA1 += wa.y * f1.y;
            accA1 += wa.z * f1.z; accA1 += wa.w * f1.w;
            accB1 += wb.x * f1.x; accB1 += wb.y * f1.y;
            accB1 += wb.z * f1.z; accB1 += wb.w * f1.w;
        }
        z2s[g0 * 128 + l]      = fmaxf(accA0, 0.0f);
        z2s[g0 * 128 + l + 64] = fmaxf(accB0, 0.0f);
        z2s[g1 * 128 + l]      = fmaxf(accA1, 0.0f);
        z2s[g1 * 128 + l + 64] = fmaxf(accB1, 0.0f);
    }

    {
        float bb = bd3[l];
        float a0 = bb, a1 = bb;
        for (int k = 0; k < 32; ++k) {
            float4 wv = *(const float4*)&Wd3[l * 128 + 4 * k];
            float4 f0 = *(const float4*)&z2s[g0 * 128 + 4 * k];
            float4 f1 = *(const float4*)&z2s[g1 * 128 + 4 * k];
            a0 += wv.x * f0.x; a0 += wv.y * f0.y; a0 += wv.z * f0.z; a0 += wv.w * f0.w;
            a1 += wv.x * f1.x; a1 += wv.y * f1.y; a1 += wv.z * f1.z; a1 += wv.w * f1.w;
        }
        z3s[g0 * 64 + l] = fmaxf(a0, 0.0f);
        z3s[g1 * 64 + l] = fmaxf(a1, 0.0f);
    }

    if (l < 8) {
        int gg = (l >> 2) ? g1 : g0;
        int o = l & 3;
        float acc = bd4[o];
        for (int c = 0; c < 64; ++c) acc += Wd4[o * 64 + c] * z3s[gg * 64 + c];
        kvs[gg * 4 + o] = 2.0f / (1.0f + expf(-acc)) + 0.2f;
    }
    if (l < 4) {
        int gg = (l >> 1) ? g1 : g0;
        int axis = l & 1;
        float ka = kvs[gg * 4 + 2 * axis + 0];
        float kb = kvs[gg * 4 + 2 * axis + 1];
        float rel = featb[gg][128 + axis];
        float vel = featb[gg][130 + axis];
        out[(base + gg) * 2 + axis] = -(ka * rel + kb * vel);
    }
}

extern "C" void kernel_launch(void* const* d_in, const int* in_sizes, int n_in,
                              void* d_out, int out_size, void* d_ws, size_t ws_size,
                              hipStream_t stream)
{
    const float* states = (const float*)d_in[0];
    const float* goals  = (const float*)d_in[1];
    const float* W1  = (const float*)d_in[2];
    const float* b1  = (const float*)d_in[3];
    const float* W2  = (const float*)d_in[4];
    const float* b2  = (const float*)d_in[5];
    const float* Wd1 = (const float*)d_in[6];
    const float* bd1 = (const float*)d_in[7];
    const float* Wd2 = (const float*)d_in[8];
    const float* bd2 = (const float*)d_in[9];
    const float* Wd3 = (const float*)d_in[10];
    const float* bd3 = (const float*)d_in[11];
    const float* Wd4 = (const float*)d_in[12];
    const float* bd4 = (const float*)d_in[13];

    int*   idx = (int*)d_ws;   // 512 KB
    float* out = (float*)d_out;

    topk_kernel<<<NAGENT, 256, 0, stream>>>(states, idx);
    fused_kernel<<<NAGENT / FAGB, 256, 0, stream>>>(states, goals, W1, b1, W2, b2,
                                                    Wd1, bd1, Wd2, bd2, Wd3, bd3,
                                                    Wd4, bd4, idx, out);
}